// Round 3
// baseline (132.780 us; speedup 1.0000x reference)
//
#include <hip/hip_runtime.h>

constexpr int NIN = 96, NOUT = 192;
constexpr int TY = 4;                       // input rows per y-tile (-> 8 output rows)
constexpr int HYR = TY + 1;                 // 5 staged rows per plane (with +1 halo)
constexpr int HXP = 98;                     // padded row length in float2 (784 B, 16B-aligned)
constexpr int F4R = NIN / 2;                // 48 float4 per input row
constexpr int NTY = NIN / TY;               // 24 y-tiles
constexpr int NBLK = 2 * NOUT * NTY;        // 9216 blocks: (b, zo, yt)
constexpr int NXCD = 8;
constexpr int CPX = NBLK / NXCD;            // 1152 (9216 % 8 == 0 -> simple swizzle bijective)

// Native vector type: __builtin_nontemporal_store rejects HIP's float4 class.
typedef float vfloat4 __attribute__((ext_vector_type(4)));

// One block = ONE output z-plane (zo) x 8 output rows = one CONTIGUOUS 12 KB store
// region. Previous version scattered each block's 48 KB over 4 planes 288 KB apart;
// with the whole grid co-resident that made ~9k sparse 1KB-burst write streams ->
// HBM row-buffer thrash (~2.1 TB/s effective write BW). Dense per-block output +
// yt-fastest ordering + XCD slab swizzle gives each XCD a dense sweeping write
// window inside its contiguous output slab. Extra input re-reads (26->53 MB) are
// served by L3 (input is 14 MB, fully resident).
__global__ __launch_bounds__(192) void resize_zoom2_v5(
        const float* __restrict__ in, float* __restrict__ out) {
    __shared__ __align__(16) float2 S[2 * HYR * HXP];   // 7840 B

    const int bid0 = blockIdx.x;
    const int bid  = (bid0 & (NXCD - 1)) * CPX + (bid0 >> 3);

    const int yt = bid % NTY;
    const int t  = bid / NTY;
    const int zo = t % NOUT;
    const int b  = t / NOUT;
    const int y0 = yt * TY;
    const int k   = zo >> 1;                 // input plane (floor)
    const int odd = zo & 1;                  // odd zo also needs plane k+1
    const int kp1 = min(k + 1, NIN - 1);
    const int R   = HYR * (1 + odd);         // 5 or 10 staged rows

    const float* vb = in + (size_t)b * ((size_t)NIN * NIN * NIN * 2);
    const float4* vin4 = (const float4*)vb;

    // x-halo element (clamp of x=96) — issue the scattered 8B loads early
    if (threadIdx.x < R) {
        int r  = threadIdx.x;
        int pl = (r < HYR) ? k : kp1;
        int yi = min(y0 + (r < HYR ? r : r - HYR), NIN - 1);
        S[r * HXP + NIN] = ((const float2*)vb)[(size_t)(pl * NIN + yi) * NIN + (NIN - 1)];
    }
    // stage R halo'd rows (clamped), float4-vectorized, coalesced
    for (int i = threadIdx.x; i < R * F4R; i += 192) {
        int r = i / F4R, col = i - r * F4R;
        int pl = (r < HYR) ? k : kp1;
        int yi = min(y0 + (r < HYR ? r : r - HYR), NIN - 1);
        float4 v = vin4[(size_t)(pl * NIN + yi) * F4R + col];
        *(float4*)((float*)(S + r * HXP) + 4 * col) = v;
    }
    __syncthreads();

    const int xp = threadIdx.x % NIN;        // 0..95 (output x-pair)
    const int yh = threadIdx.x / NIN;        // 0..1
    vfloat4* vout = (vfloat4*)out;
    // float4 index of (zo, yo = 2*y0 + yh, xp); block's 16 wave-stores tile a
    // contiguous 12 KB region (rows 8*yt .. 8*yt+7 of plane zo).
    size_t ob = ((size_t)(b * NOUT + zo) * NOUT + (2 * y0 + yh)) * (NOUT / 2) + xp;

    if (!odd) {
        // even zo: z-weight hits plane k only
        #pragma unroll
        for (int y2 = 0; y2 < TY; ++y2) {
            int yo = 2 * y2 + yh;
            int yA = yo >> 1, yB = yA + (yo & 1);
            float2 aA = S[yA * HXP + xp],     aB = S[yB * HXP + xp];
            float2 cA = S[yA * HXP + xp + 1], cB = S[yB * HXP + xp + 1];
            float sx  = aA.x + aB.x, sy  = aA.y + aB.y;
            float scx = cA.x + cB.x, scy = cA.y + cB.y;
            vfloat4 e = { 0.5f * sx, 0.5f * sy,
                          0.25f * (sx + scx), 0.25f * (sy + scy) };
            __builtin_nontemporal_store(e, &vout[ob + (size_t)y2 * NOUT]);
        }
    } else {
        // odd zo: average of planes k and k+1
        #pragma unroll
        for (int y2 = 0; y2 < TY; ++y2) {
            int yo = 2 * y2 + yh;
            int yA = yo >> 1, yB = yA + (yo & 1);
            float2 aA = S[yA * HXP + xp],           aB = S[yB * HXP + xp];
            float2 cA = S[yA * HXP + xp + 1],       cB = S[yB * HXP + xp + 1];
            float2 bA = S[(HYR + yA) * HXP + xp],   bB = S[(HYR + yB) * HXP + xp];
            float2 dA = S[(HYR + yA) * HXP + xp + 1], dB = S[(HYR + yB) * HXP + xp + 1];
            float ux = aA.x + aB.x + bA.x + bB.x;
            float uy = aA.y + aB.y + bA.y + bB.y;
            float vx = ux + cA.x + cB.x + dA.x + dB.x;
            float vy = uy + cA.y + cB.y + dA.y + dB.y;
            vfloat4 e = { 0.25f * ux, 0.25f * uy,
                          0.125f * vx, 0.125f * vy };
            __builtin_nontemporal_store(e, &vout[ob + (size_t)y2 * NOUT]);
        }
    }
}

extern "C" void kernel_launch(void* const* d_in, const int* in_sizes, int n_in,
                              void* d_out, int out_size, void* d_ws, size_t ws_size,
                              hipStream_t stream) {
    const float* in = (const float*)d_in[0];
    float* out = (float*)d_out;
    resize_zoom2_v5<<<NBLK, 192, 0, stream>>>(in, out);
}

// Round 4
// 123.938 us; speedup vs baseline: 1.0713x; 1.0713x over previous
//
#include <hip/hip_runtime.h>

// v6 = v3 structure (best measured: 122.9/123.5 us) with TZ=4:
//  - cached float4 stores (NT measured ~+2us worse in R2), no XCD swizzle (neutral R2)
//  - input tile (z,y) = 4x4, full x: halo read amplification (5/4)(5/4)=1.5625x
//    (v3 was (3/2)(5/4)=1.875x) -> 22.1 MB total reads vs 26.5 MB
//  - 1152 blocks x 192 thr; LDS 19.6 KB -> 8 blocks/CU (24 waves), plenty to hide latency
constexpr int NIN = 96, NOUT = 192;
constexpr int TZ = 4, TY = 4;              // input tile (z,y), full x
constexpr int HZ = TZ + 1, HY = TY + 1;    // 5, 5 (with +1 halo)
constexpr int ROWS = HZ * HY;              // 25 staged rows
constexpr int HXP = 98;                    // padded row length in float2 (784 B, 16B-aligned)
constexpr int F4R = NIN / 2;               // 48 float4 per input row
constexpr int NTZ = NIN / TZ, NTY = NIN / TY;  // 24, 24
constexpr int NBLK = 2 * NTZ * NTY;        // 1152

__global__ __launch_bounds__(192) void resize_zoom2_v6(
        const float* __restrict__ in, float* __restrict__ out) {
    __shared__ __align__(16) float2 S[ROWS * HXP];   // 19600 B

    const int bid = blockIdx.x;
    const int yt = bid % NTY;
    const int tt = bid / NTY;
    const int zt = tt % NTZ;
    const int b  = tt / NTZ;
    const int z0 = zt * TZ, y0 = yt * TY;

    const float* vb = in + (size_t)b * ((size_t)NIN * NIN * NIN * 2);
    const float4* vin4 = (const float4*)vb;

    // ---- x-halo element (clamp of x=96): scattered 8B loads, issue early
    if (threadIdx.x < ROWS) {
        int r = threadIdx.x;
        int zi = min(z0 + r / HY, NIN - 1);
        int yi = min(y0 + r % HY, NIN - 1);
        S[r * HXP + NIN] = ((const float2*)vb)[(size_t)(zi * NIN + yi) * NIN + (NIN - 1)];
    }
    // ---- stage 25 halo'd rows (clamped), float4-vectorized, coalesced
    for (int i = threadIdx.x; i < ROWS * F4R; i += 192) {
        int r = i / F4R, col = i - r * F4R;
        int zi = min(z0 + r / HY, NIN - 1);
        int yi = min(y0 + (r - (r / HY) * HY), NIN - 1);
        float4 v = vin4[(size_t)(zi * NIN + yi) * F4R + col];
        *(float4*)((float*)(S + r * HXP) + 4 * col) = v;
    }
    __syncthreads();

    // ---- compute: thread owns fixed (yhalf, xp); rolls along z carrying plane sums
    const int xp = threadIdx.x % NIN;       // 0..95  (output x-pair)
    const int yh = threadIdx.x / NIN;       // 0..1
    float4* vout = (float4*)out;
    constexpr size_t ZSTR = (size_t)NOUT * (NOUT / 2);   // float4 per output z-plane
    // float4 index of (zo=2*z0, yo=2*y0+yh, xp); across threads this is base + tid (contiguous)
    size_t ob = ((size_t)(b * NOUT + 2 * z0) * NOUT + (2 * y0 + yh)) * (NOUT / 2) + xp;

    #pragma unroll
    for (int y2 = 0; y2 < TY; ++y2) {
        const int yo = 2 * y2 + yh;
        const int yA = yo >> 1, yB = yA + (yo & 1);
        const float2* pA = S + yA * HXP;    // plane stride = HY*HXP
        const float2* pB = S + yB * HXP;

        float2 aA = pA[xp],     aB = pB[xp];
        float2 cA = pA[xp + 1], cB = pB[xp + 1];
        float sy_x  = aA.x + aB.x, sy_y  = aA.y + aB.y;   // plane-k y-sum at x
        float syc_x = cA.x + cB.x, syc_y = cA.y + cB.y;   // plane-k y-sum at x+1
        size_t o = ob + (size_t)y2 * NOUT;  // +2 output rows per y2

        #pragma unroll
        for (int k = 0; k < TZ; ++k) {
            const float2* qA = pA + (k + 1) * HY * HXP;
            const float2* qB = pB + (k + 1) * HY * HXP;
            float2 bA = qA[xp],     bB = qB[xp];
            float2 dA = qA[xp + 1], dB = qB[xp + 1];
            float ty_x  = bA.x + bB.x, ty_y  = bA.y + bB.y;  // plane-(k+1) sums
            float tyc_x = dA.x + dB.x, tyc_y = dA.y + dB.y;

            // zo = 2k (even z): plane k only
            vout[o + (size_t)(2 * k) * ZSTR] =
                make_float4(0.5f * sy_x, 0.5f * sy_y,
                            0.25f * (sy_x + syc_x), 0.25f * (sy_y + syc_y));
            // zo = 2k+1 (odd z): planes k and k+1
            float ux = sy_x + ty_x, uy = sy_y + ty_y;
            float vx = ux + syc_x + tyc_x, vy = uy + syc_y + tyc_y;
            vout[o + (size_t)(2 * k + 1) * ZSTR] =
                make_float4(0.25f * ux, 0.25f * uy, 0.125f * vx, 0.125f * vy);

            sy_x = ty_x; sy_y = ty_y; syc_x = tyc_x; syc_y = tyc_y;
        }
    }
}

extern "C" void kernel_launch(void* const* d_in, const int* in_sizes, int n_in,
                              void* d_out, int out_size, void* d_ws, size_t ws_size,
                              hipStream_t stream) {
    const float* in = (const float*)d_in[0];
    float* out = (float*)d_out;
    resize_zoom2_v6<<<NBLK, 192, 0, stream>>>(in, out);
}